// Round 1
// baseline (27.694 us; speedup 1.0000x reference)
//
#include <hip/hip_runtime.h>

// Problem constants (from reference)
#define BAGS   16384
#define DIM    3
#define KIN    13

// One wave (64 lanes) per bag: gather rows, reduce, write mean x3 copies.
__global__ __launch_bounds__(256) void eb_kernel(
    const int* __restrict__ idxs, const int* __restrict__ offs,
    const float* __restrict__ W, float* __restrict__ out, int n_total)
{
    int wave = (int)((blockIdx.x * blockDim.x + threadIdx.x) >> 6);
    int lane = (int)(threadIdx.x & 63);
    if (wave >= BAGS) return;

    int start = offs[wave];
    int end   = (wave + 1 < BAGS) ? offs[wave + 1] : n_total;
    int cnt   = end - start;

    float s0 = 0.f, s1 = 0.f, s2 = 0.f;
    for (int i = start + lane; i < end; i += 64) {
        int idx = idxs[i];
        const float* row = W + (size_t)idx * DIM;
        s0 += row[0];
        s1 += row[1];
        s2 += row[2];
    }

    // 64-lane butterfly-free down reduction
    #pragma unroll
    for (int off = 32; off > 0; off >>= 1) {
        s0 += __shfl_down(s0, off);
        s1 += __shfl_down(s1, off);
        s2 += __shfl_down(s2, off);
    }

    if (lane == 0) {
        float inv = 1.0f / (float)cnt;
        float e0 = s0 * inv, e1 = s1 * inv, e2 = s2 * inv;
        float* o = out + (size_t)wave * 12;
        o[0] = e0; o[1] = e1; o[2] = e2;
        o[3] = e0; o[4] = e1; o[5] = e2;
        o[6] = e0; o[7] = e1; o[8] = e2;
    }
}

// One thread per bag: 13 -> 12 -> 6 -> 3 affine chain (no activations).
__global__ __launch_bounds__(256) void mlp_kernel(
    const float* __restrict__ x,
    const float* __restrict__ w0, const float* __restrict__ b0,
    const float* __restrict__ w1, const float* __restrict__ b1,
    const float* __restrict__ w2, const float* __restrict__ b2,
    float* __restrict__ out)
{
    int b = (int)(blockIdx.x * blockDim.x + threadIdx.x);
    if (b >= BAGS) return;

    float xi[KIN];
    #pragma unroll
    for (int k = 0; k < KIN; ++k) xi[k] = x[(size_t)b * KIN + k];

    float h0[12];
    #pragma unroll
    for (int j = 0; j < 12; ++j) {
        float acc = b0[j];
        #pragma unroll
        for (int k = 0; k < KIN; ++k) acc += w0[j * KIN + k] * xi[k];
        h0[j] = acc;
    }

    float h1[6];
    #pragma unroll
    for (int j = 0; j < 6; ++j) {
        float acc = b1[j];
        #pragma unroll
        for (int k = 0; k < 12; ++k) acc += w1[j * 12 + k] * h0[k];
        h1[j] = acc;
    }

    float* o = out + (size_t)b * 12 + 9;
    #pragma unroll
    for (int j = 0; j < 3; ++j) {
        float acc = b2[j];
        #pragma unroll
        for (int k = 0; k < 6; ++k) acc += w2[j * 6 + k] * h1[k];
        o[j] = acc;
    }
}

extern "C" void kernel_launch(void* const* d_in, const int* in_sizes, int n_in,
                              void* d_out, int out_size, void* d_ws, size_t ws_size,
                              hipStream_t stream) {
    const int*   eb_input   = (const int*)  d_in[0];   // [N]
    const int*   eb_offset  = (const int*)  d_in[1];   // [B]
    const float* mlp_input  = (const float*)d_in[2];   // [B,13]
    const float* emb_weight = (const float*)d_in[3];   // [V,3]
    const float* w0 = (const float*)d_in[4];
    const float* b0 = (const float*)d_in[5];
    const float* w1 = (const float*)d_in[6];
    const float* b1 = (const float*)d_in[7];
    const float* w2 = (const float*)d_in[8];
    const float* b2 = (const float*)d_in[9];
    float* out = (float*)d_out;

    int n_total = in_sizes[0];

    // EB: one wave per bag, 4 waves per 256-thread block.
    int eb_blocks = BAGS / 4;
    eb_kernel<<<eb_blocks, 256, 0, stream>>>(eb_input, eb_offset, emb_weight, out, n_total);

    // MLP: one thread per bag.
    int mlp_blocks = (BAGS + 255) / 256;
    mlp_kernel<<<mlp_blocks, 256, 0, stream>>>(mlp_input, w0, b0, w1, b1, w2, b2, out);
}

// Round 2
// 24.628 us; speedup vs baseline: 1.1245x; 1.1245x over previous
//
#include <hip/hip_runtime.h>

#define BAGS       16384
#define KIN        13
#define EB_BLOCKS  1024   // 256 thr = 4 waves/block; 16 lanes/bag -> 16 bags/block
#define MLP_BLOCKS 64     // 16384 / 256

__global__ __launch_bounds__(256) void fused_kernel(
    const int* __restrict__ idxs, const int* __restrict__ offs,
    const float* __restrict__ W, const float* __restrict__ x,
    const float* __restrict__ w0, const float* __restrict__ b0,
    const float* __restrict__ w1, const float* __restrict__ b1,
    const float* __restrict__ w2, const float* __restrict__ b2,
    float* __restrict__ out, int n_total)
{
    if (blockIdx.x < EB_BLOCKS) {
        // ---- EmbeddingBag mean: 16 lanes per bag ----
        int tid = (int)(blockIdx.x * 256 + threadIdx.x);
        int bag = tid >> 4;                 // global 16-lane group id == bag id
        int sl  = (int)(threadIdx.x & 15);

        int start = offs[bag];
        int end   = (bag + 1 < BAGS) ? offs[bag + 1] : n_total;
        int cnt   = end - start;

        float s0 = 0.f, s1 = 0.f, s2 = 0.f;

        if (cnt == 50) {
            // fast path: 3 full strides of 16 + tail of 2, all loads issued early
            int i0 = start + sl;
            int ia = idxs[i0];
            int ib = idxs[i0 + 16];
            int ic = idxs[i0 + 32];
            const float* ra = W + (size_t)ia * 3;
            const float* rb = W + (size_t)ib * 3;
            const float* rc = W + (size_t)ic * 3;
            float a0 = ra[0], a1 = ra[1], a2 = ra[2];
            float e0 = rb[0], e1 = rb[1], e2 = rb[2];
            float c0 = rc[0], c1 = rc[1], c2 = rc[2];
            s0 = a0 + e0 + c0;
            s1 = a1 + e1 + c1;
            s2 = a2 + e2 + c2;
            if (sl < 2) {
                int idd = idxs[i0 + 48];
                const float* rd = W + (size_t)idd * 3;
                s0 += rd[0]; s1 += rd[1]; s2 += rd[2];
            }
        } else {
            for (int i = start + sl; i < end; i += 16) {
                int idx = idxs[i];
                const float* r = W + (size_t)idx * 3;
                s0 += r[0]; s1 += r[1]; s2 += r[2];
            }
        }

        // butterfly reduce within each 16-lane group -> all lanes hold sums
        #pragma unroll
        for (int m = 8; m >= 1; m >>= 1) {
            s0 += __shfl_xor(s0, m, 16);
            s1 += __shfl_xor(s1, m, 16);
            s2 += __shfl_xor(s2, m, 16);
        }

        if (sl < 9) {
            float inv = 1.0f / (float)cnt;
            int c = sl % 3;  // out columns 0..8 are (e0,e1,e2) x3
            float e = (c == 0 ? s0 : (c == 1 ? s1 : s2)) * inv;
            out[(size_t)bag * 12 + sl] = e;
        }
    } else {
        // ---- MLP: one thread per bag, 13 -> 12 -> 6 -> 3 affine ----
        int b = (int)((blockIdx.x - EB_BLOCKS) * 256 + threadIdx.x);
        if (b >= BAGS) return;

        float xi[KIN];
        #pragma unroll
        for (int k = 0; k < KIN; ++k) xi[k] = x[(size_t)b * KIN + k];

        float h0[12];
        #pragma unroll
        for (int j = 0; j < 12; ++j) {
            float acc = b0[j];
            #pragma unroll
            for (int k = 0; k < KIN; ++k) acc += w0[j * KIN + k] * xi[k];
            h0[j] = acc;
        }

        float h1[6];
        #pragma unroll
        for (int j = 0; j < 6; ++j) {
            float acc = b1[j];
            #pragma unroll
            for (int k = 0; k < 12; ++k) acc += w1[j * 12 + k] * h0[k];
            h1[j] = acc;
        }

        float* o = out + (size_t)b * 12 + 9;
        #pragma unroll
        for (int j = 0; j < 3; ++j) {
            float acc = b2[j];
            #pragma unroll
            for (int k = 0; k < 6; ++k) acc += w2[j * 6 + k] * h1[k];
            o[j] = acc;
        }
    }
}

extern "C" void kernel_launch(void* const* d_in, const int* in_sizes, int n_in,
                              void* d_out, int out_size, void* d_ws, size_t ws_size,
                              hipStream_t stream) {
    const int*   eb_input   = (const int*)  d_in[0];   // [N]
    const int*   eb_offset  = (const int*)  d_in[1];   // [B]
    const float* mlp_input  = (const float*)d_in[2];   // [B,13]
    const float* emb_weight = (const float*)d_in[3];   // [V,3]
    const float* w0 = (const float*)d_in[4];
    const float* b0 = (const float*)d_in[5];
    const float* w1 = (const float*)d_in[6];
    const float* b1 = (const float*)d_in[7];
    const float* w2 = (const float*)d_in[8];
    const float* b2 = (const float*)d_in[9];
    float* out = (float*)d_out;

    int n_total = in_sizes[0];

    fused_kernel<<<EB_BLOCKS + MLP_BLOCKS, 256, 0, stream>>>(
        eb_input, eb_offset, emb_weight, mlp_input,
        w0, b0, w1, b1, w2, b2, out, n_total);
}

// Round 3
// 24.079 us; speedup vs baseline: 1.1501x; 1.0228x over previous
//
#include <hip/hip_runtime.h>

#define BAGS       16384
#define KIN        13
// 32 lanes per bag, 8 bags per 256-thread block -> 2048 EB blocks (≈32 waves/CU)
#define EB_BLOCKS  (BAGS / 8)
#define MLP_BLOCKS (BAGS / 256)

__global__ __launch_bounds__(256) void fused_kernel(
    const int* __restrict__ idxs, const int* __restrict__ offs,
    const float* __restrict__ W, const float* __restrict__ x,
    const float* __restrict__ w0, const float* __restrict__ b0,
    const float* __restrict__ w1, const float* __restrict__ b1,
    const float* __restrict__ w2, const float* __restrict__ b2,
    float* __restrict__ out, int n_total)
{
    if (blockIdx.x < EB_BLOCKS) {
        // ---- EmbeddingBag mean: 32 lanes per bag ----
        int bag = (int)(blockIdx.x * 8 + (threadIdx.x >> 5));
        int sl  = (int)(threadIdx.x & 31);

        int start = offs[bag];
        int end   = (bag + 1 < BAGS) ? offs[bag + 1] : n_total;
        int cnt   = end - start;

        float s0 = 0.f, s1 = 0.f, s2 = 0.f;

        if (cnt == 50) {
            // lanes 0..31 handle slot sl; lanes 0..17 also handle slot sl+32.
            int i0 = start + sl;
            int ia = __builtin_nontemporal_load(&idxs[i0]);
            int ib = 0;
            bool two = (sl < 18);
            if (two) ib = __builtin_nontemporal_load(&idxs[i0 + 32]);
            const float* ra = W + (size_t)ia * 3;
            float a0 = ra[0], a1 = ra[1], a2 = ra[2];
            if (two) {
                const float* rb = W + (size_t)ib * 3;
                s0 = rb[0]; s1 = rb[1]; s2 = rb[2];
            }
            s0 += a0; s1 += a1; s2 += a2;
        } else {
            for (int i = start + sl; i < end; i += 32) {
                int idx = idxs[i];
                const float* r = W + (size_t)idx * 3;
                s0 += r[0]; s1 += r[1]; s2 += r[2];
            }
        }

        // butterfly reduce within each 32-lane group
        #pragma unroll
        for (int m = 16; m >= 1; m >>= 1) {
            s0 += __shfl_xor(s0, m, 32);
            s1 += __shfl_xor(s1, m, 32);
            s2 += __shfl_xor(s2, m, 32);
        }

        if (sl < 9) {
            float inv = 1.0f / (float)cnt;
            int c = sl % 3;  // out columns 0..8 are (e0,e1,e2) x3
            float e = (c == 0 ? s0 : (c == 1 ? s1 : s2)) * inv;
            out[(size_t)bag * 12 + sl] = e;
        }
    } else {
        // ---- MLP: one thread per bag, 13 -> 12 -> 6 -> 3 affine ----
        int b = (int)((blockIdx.x - EB_BLOCKS) * 256 + threadIdx.x);
        if (b >= BAGS) return;

        float xi[KIN];
        #pragma unroll
        for (int k = 0; k < KIN; ++k) xi[k] = x[(size_t)b * KIN + k];

        float h0[12];
        #pragma unroll
        for (int j = 0; j < 12; ++j) {
            float acc = b0[j];
            #pragma unroll
            for (int k = 0; k < KIN; ++k) acc += w0[j * KIN + k] * xi[k];
            h0[j] = acc;
        }

        float h1[6];
        #pragma unroll
        for (int j = 0; j < 6; ++j) {
            float acc = b1[j];
            #pragma unroll
            for (int k = 0; k < 12; ++k) acc += w1[j * 12 + k] * h0[k];
            h1[j] = acc;
        }

        float* o = out + (size_t)b * 12 + 9;
        #pragma unroll
        for (int j = 0; j < 3; ++j) {
            float acc = b2[j];
            #pragma unroll
            for (int k = 0; k < 6; ++k) acc += w2[j * 6 + k] * h1[k];
            o[j] = acc;
        }
    }
}

extern "C" void kernel_launch(void* const* d_in, const int* in_sizes, int n_in,
                              void* d_out, int out_size, void* d_ws, size_t ws_size,
                              hipStream_t stream) {
    const int*   eb_input   = (const int*)  d_in[0];   // [N]
    const int*   eb_offset  = (const int*)  d_in[1];   // [B]
    const float* mlp_input  = (const float*)d_in[2];   // [B,13]
    const float* emb_weight = (const float*)d_in[3];   // [V,3]
    const float* w0 = (const float*)d_in[4];
    const float* b0 = (const float*)d_in[5];
    const float* w1 = (const float*)d_in[6];
    const float* b1 = (const float*)d_in[7];
    const float* w2 = (const float*)d_in[8];
    const float* b2 = (const float*)d_in[9];
    float* out = (float*)d_out;

    int n_total = in_sizes[0];

    fused_kernel<<<EB_BLOCKS + MLP_BLOCKS, 256, 0, stream>>>(
        eb_input, eb_offset, emb_weight, mlp_input,
        w0, b0, w1, b1, w2, b2, out, n_total);
}